// Round 11
// baseline (137.789 us; speedup 1.0000x reference)
//
#include <hip/hip_runtime.h>

typedef unsigned short ushort;
typedef short bf16x8 __attribute__((ext_vector_type(8)));   // 8 bf16 in 4 VGPRs
typedef float f32x4 __attribute__((ext_vector_type(4)));

static __device__ __forceinline__ ushort f2b(float f) {
  unsigned u = __builtin_bit_cast(unsigned, f);
  u = (u + 0x7fffu + ((u >> 16) & 1u)) >> 16;
  return (ushort)u;
}
static __device__ __forceinline__ float b2f(ushort b) {
  return __builtin_bit_cast(float, (unsigned)b << 16);
}

// async global->LDS, 16B per lane; LDS dest is wave-uniform base + lane*16
static __device__ __forceinline__ void gll16(const ushort* g, ushort* l) {
  __builtin_amdgcn_global_load_lds(
      (const __attribute__((address_space(1))) void*)g,
      (__attribute__((address_space(3))) void*)l, 16, 0, 0);
}

// ---------------------------------------------------------------------------
// prep: weight transposes only (x-transpose now fused into gemm_qkv).
// 512 blocks: 192 wqkv + 64 wproj + 128 wfc1 + 128 wfc2.
// ---------------------------------------------------------------------------
__global__ __launch_bounds__(256) void prep_kernel(
    const float* __restrict__ w_qkv, const float* __restrict__ w_proj,
    const float* __restrict__ w_fc1, const float* __restrict__ w_fc2,
    ushort* __restrict__ wqkvT, ushort* __restrict__ wprojT,
    ushort* __restrict__ wfc1T, ushort* __restrict__ wfc2T)
{
  __shared__ float tile[32][33];
  int t = blockIdx.x;
  const float* src; ushort* dst; int R, Nc, r0, c0;
  if (t < 192)               { src = w_qkv;  dst = wqkvT;  R = 256; Nc = 768;  r0 = (t / 24) * 32; c0 = (t % 24) * 32; }
  else if ((t -= 192) < 64)  { src = w_proj; dst = wprojT; R = 256; Nc = 256;  r0 = (t / 8) * 32;  c0 = (t % 8) * 32; }
  else if ((t -= 64) < 128)  { src = w_fc1;  dst = wfc1T;  R = 256; Nc = 512;  r0 = (t / 16) * 32; c0 = (t % 16) * 32; }
  else           { t -= 128;   src = w_fc2;  dst = wfc2T;  R = 512; Nc = 256;  r0 = (t / 8) * 32;  c0 = (t % 8) * 32; }

  const int tx = threadIdx.x & 31, ty = threadIdx.x >> 5;
  #pragma unroll
  for (int i = 0; i < 4; i++)
    tile[ty + i * 8][tx] = src[(size_t)(r0 + ty + i * 8) * Nc + c0 + tx];
  __syncthreads();
  #pragma unroll
  for (int i = 0; i < 4; i++)
    dst[(size_t)(c0 + ty + i * 8) * R + r0 + tx] = f2b(tile[tx][ty + i * 8]);
}

// ---------------------------------------------------------------------------
// qkv GEMM, 128x128-tile engine, A-transpose FUSED: A-operand reads x (f32,
// CHW = A^T) directly, converts+transposes in registers, writes swizzled
// bf16 tile to LDS (ds_write_b128, same (r&7)<<4 XOR as the read side).
// B-operand staged via gll16 as before. Eliminates the xb tensor (~50MB of
// prep traffic). f2b here is bit-identical to prep's -> results unchanged.
// ---------------------------------------------------------------------------
__global__ __launch_bounds__(256) void gemm_qkv(
    const float* __restrict__ x, const ushort* __restrict__ Bt,
    const float* __restrict__ bias,
    ushort* __restrict__ C0, ushort* __restrict__ C1)
{
  __shared__ __attribute__((aligned(16))) ushort As[128 * 64];   // 16KB
  __shared__ __attribute__((aligned(16))) ushort Bs[128 * 64];   // 16KB

  const int bm = blockIdx.y * 128;
  const int bn = blockIdx.x * 128;
  const int w    = threadIdx.x >> 6;
  const int lane = threadIdx.x & 63;
  const int lm = lane & 15;
  const int kq = lane >> 4;                    // 0..3
  const int wm = (w & 1) * 64;
  const int wn = (w >> 1) * 64;

  // B staging (gll16): chunk = 8 rows x 128B
  const int rl  = lane >> 3;                   // row within chunk (0..7)
  const int cbx = (lane & 7) << 4;             // byte col within 128B row
  const int xr  = (lm & 7) << 4;               // read-side XOR

  // A staging (register transpose): thread covers 4 m x 8 k
  const int kg = threadIdx.x & 7;              // k-octet 0..7 (k = kg*8+j)
  const int mg = threadIdx.x >> 3;             // m-quad 0..31 (m = mg*4+mi)

  f32x4 acc[4][4] = {};

  #pragma unroll
  for (int k0 = 0; k0 < 256; k0 += 64) {
    // ---- B: 16 x 1KB chunks via gll16 (unchanged) ----
    #pragma unroll
    for (int s = 0; s < 4; s++) {
      const int c = w * 4 + s;                                // chunk 0..15
      const int r = c * 8 + rl;                               // tile row 0..127
      const int off = (cbx ^ ((r & 7) << 4)) >> 1;            // swz src (ushorts)
      gll16(Bt + (size_t)(bn + r) * 256 + k0 + off, Bs + c * 512);
    }
    // ---- A: f32 read (coalesced along m) -> bf16 pack -> swizzled LDS ----
    {
      float4 v[8];
      #pragma unroll
      for (int j = 0; j < 8; j++)
        v[j] = *(const float4*)(x + (size_t)(k0 + kg * 8 + j) * 8192 + bm + mg * 4);
      #pragma unroll
      for (int mi = 0; mi < 4; mi++) {
        const int r = mg * 4 + mi;
        const float* f0 = (const float*)&v[0];
        unsigned p0 = (unsigned)f2b(((const float*)&v[0])[mi]) |
                      ((unsigned)f2b(((const float*)&v[1])[mi]) << 16);
        unsigned p1 = (unsigned)f2b(((const float*)&v[2])[mi]) |
                      ((unsigned)f2b(((const float*)&v[3])[mi]) << 16);
        unsigned p2 = (unsigned)f2b(((const float*)&v[4])[mi]) |
                      ((unsigned)f2b(((const float*)&v[5])[mi]) << 16);
        unsigned p3 = (unsigned)f2b(((const float*)&v[6])[mi]) |
                      ((unsigned)f2b(((const float*)&v[7])[mi]) << 16);
        uint4 pk; pk.x = p0; pk.y = p1; pk.z = p2; pk.w = p3;
        *(uint4*)((char*)As + r * 128 + ((kg << 4) ^ ((r & 7) << 4))) = pk;
        (void)f0;
      }
    }
    __syncthreads();

    #pragma unroll
    for (int ks = 0; ks < 2; ks++) {
      const int cs = (ks * 64 + (kq << 4)) ^ xr;              // byte col, swz
      bf16x8 a[4], b[4];
      #pragma unroll
      for (int i = 0; i < 4; i++) {
        a[i] = *(const bf16x8*)((const char*)As + (wm + i * 16 + lm) * 128 + cs);
        b[i] = *(const bf16x8*)((const char*)Bs + (wn + i * 16 + lm) * 128 + cs);
      }
      #pragma unroll
      for (int i = 0; i < 4; i++)
        #pragma unroll
        for (int j = 0; j < 4; j++)
          acc[i][j] = __builtin_amdgcn_mfma_f32_16x16x32_bf16(a[i], b[j], acc[i][j], 0, 0, 0);
    }
    __syncthreads();
  }

  #pragma unroll
  for (int ti = 0; ti < 4; ti++) {
    #pragma unroll
    for (int tj = 0; tj < 4; tj++) {
      const int n  = bn + wn + tj * 16 + lm;
      const int m0 = bm + wm + ti * 16 + kq * 4;
      if (n < 512) {
        #pragma unroll
        for (int r = 0; r < 4; r++)
          C0[(size_t)(m0 + r) * 768 + n] = f2b(acc[ti][tj][r] + bias[n]);
      } else {
        ushort4 st;
        st.x = f2b(acc[ti][tj][0] + bias[n]);
        st.y = f2b(acc[ti][tj][1] + bias[n]);
        st.z = f2b(acc[ti][tj][2] + bias[n]);
        st.w = f2b(acc[ti][tj][3] + bias[n]);
        *(ushort4*)(C1 + (size_t)(n - 512) * 8192 + m0) = st;
      }
    }
  }
}

// ---------------------------------------------------------------------------
// MFMA neighborhood attention v3 (unchanged).
// ---------------------------------------------------------------------------
__global__ __launch_bounds__(256, 4) void natt_mfma(
    const ushort* __restrict__ qkv, const ushort* __restrict__ vT,
    const float* __restrict__ rpb, ushort* __restrict__ att)
{
  __shared__ __attribute__((aligned(16))) ushort Plds[4][7][16][40];
  __shared__ float Rlds[4][176];

  const int w    = threadIdx.x >> 6;
  const int lane = threadIdx.x & 63;
  const int l  = lane & 15;
  const int q  = lane >> 4;
  const int tile = blockIdx.x;            // 0..511
  const int n    = blockIdx.y * 4 + w;    // head 0..7
  const int ph  = tile >> 3;
  const int pw0 = (tile & 7) << 4;
  const int p0  = ph * 128 + pw0;

  int sh = ph - 3;  sh = sh < 0 ? 0 : (sh > 57 ? 57 : sh);
  int sb = pw0 - 3; sb = sb < 0 ? 0 : sb;
  const int sba = sb & ~7;                // 16B-aligned span base

  const float L2E = 1.44269504f;
  for (int idx = lane; idx < 169; idx += 64)
    Rlds[w][idx] = rpb[n * 169 + idx] * L2E;

  bf16x8 qf = *(const bf16x8*)(qkv + (size_t)(p0 + l) * 768 + n * 32 + q * 8);

  const float KSC = 0.17677669529663689f * 1.44269504f;  // hd^-0.5 * log2(e)
  const int relh0 = sh - ph + 6;          // 0..6
  float rsum[4] = {0.f, 0.f, 0.f, 0.f};

  #pragma unroll
  for (int h = 0; h < 2; h++) {
    f32x4 s[7] = {};
    #pragma unroll
    for (int i = 0; i < 7; i++) {
      const int rowp = (sh + i) * 128;
      int jc = sba + h * 16 + l;
      jc = jc > 127 ? 127 : jc;           // clamp addr; junk masked below
      bf16x8 kf = *(const bf16x8*)(qkv + (size_t)(rowp + jc) * 768 + 256 + n * 32 + q * 8);
      s[i] = __builtin_amdgcn_mfma_f32_16x16x32_bf16(qf, kf, s[i], 0, 0, 0);
    }
    #pragma unroll
    for (int r = 0; r < 4; r++) {
      const int pw = pw0 + q * 4 + r;
      int sw = pw - 3; sw = sw < 0 ? 0 : (sw > 121 ? 121 : sw);
      const int jc = sba + h * 16 + l;
      const bool valid = (unsigned)(jc - sw) <= 6u;
      int relw = jc - pw + 6;
      relw = relw < 0 ? 0 : (relw > 12 ? 12 : relw);
      #pragma unroll
      for (int i = 0; i < 7; i++) {
        float b = Rlds[w][(relh0 + i) * 13 + relw];
        float v = s[i][r] * KSC + b;
        v = valid ? v : -1e30f;
        float e = exp2f(v);
        rsum[r] += e;
        Plds[w][i][q * 4 + r][h * 16 + l] = f2b(e);
      }
    }
  }

  #pragma unroll
  for (int r = 0; r < 4; r++) {
    rsum[r] += __shfl_xor(rsum[r], 1);
    rsum[r] += __shfl_xor(rsum[r], 2);
    rsum[r] += __shfl_xor(rsum[r], 4);
    rsum[r] += __shfl_xor(rsum[r], 8);
  }

  f32x4 o[2] = {};
  #pragma unroll
  for (int i = 0; i < 7; i++) {
    bf16x8 pf = *(const bf16x8*)(&Plds[w][i][l][q * 8]);
    const int rowp = (sh + i) * 128;
    #pragma unroll
    for (int dh = 0; dh < 2; dh++) {
      bf16x8 vf = *(const bf16x8*)(vT + (size_t)(n * 32 + dh * 16 + l) * 8192
                                      + rowp + sba + q * 8);
      o[dh] = __builtin_amdgcn_mfma_f32_16x16x32_bf16(pf, vf, o[dh], 0, 0, 0);
    }
  }

  #pragma unroll
  for (int r = 0; r < 4; r++) {
    const float inv = 1.0f / rsum[r];
    #pragma unroll
    for (int dh = 0; dh < 2; dh++)
      att[(size_t)(p0 + q * 4 + r) * 256 + n * 32 + dh * 16 + l] = f2b(o[dh][r] * inv);
  }
}

// ---------------------------------------------------------------------------
// Fused proj + fc1(gelu) + fc2 + both residuals (v1, best measured).
// 256 blocks x 512 threads, 32 rows/block; x1/h LDS-resident.
// LDS: As 8K + Bs 64K + X1 16K + Hs 16K = 104KB.
// ---------------------------------------------------------------------------
__global__ __launch_bounds__(512) void mlp_fused(
    const ushort* __restrict__ att, const ushort* __restrict__ wprojT,
    const ushort* __restrict__ wfc1T, const ushort* __restrict__ wfc2T,
    const float* __restrict__ b_proj, const float* __restrict__ b_fc1,
    const float* __restrict__ b_fc2, const float* __restrict__ xres,
    float* __restrict__ out)
{
  __shared__ __attribute__((aligned(16))) ushort As[32 * 128];    //  8KB
  __shared__ __attribute__((aligned(16))) ushort Bs[256 * 128];   // 64KB
  __shared__ __attribute__((aligned(16))) ushort X1[32 * 256];    // 16KB
  __shared__ __attribute__((aligned(16))) ushort Hs[32 * 256];    // 16KB

  const int bm   = blockIdx.x * 32;
  const int t    = threadIdx.x;
  const int w    = t >> 6;
  const int lane = t & 63;
  const int lm   = lane & 15;
  const int kq   = lane >> 4;          // 0..3
  const int wm   = (w & 1) * 16;       // wave m-offset (0/16)
  const int wn   = (w >> 1) * 64;      // wave n-offset (0/64/128/192)

  const int rl  = lane >> 4;
  const int swl = (lane & 15) << 3;

  f32x4 acc_o[4] = {};                 // fc2 accumulator, persists all phases

  // ---------------- proj: x1 = att @ wprojT^T + b_proj + x(chw) ------------
  {
    f32x4 acc_p[4] = {};
    #pragma unroll
    for (int kt = 0; kt < 2; kt++) {
      {
        const int m = w * 4 + rl;                         // As: 8 chunks
        gll16(att + (size_t)(bm + m) * 256 + kt * 128 + (swl ^ ((m & 7) << 3)),
              As + w * 512);
      }
      #pragma unroll
      for (int s = 0; s < 8; s++) {                       // Bs: 64 chunks
        const int c = w * 8 + s;
        const int n = c * 4 + rl;
        gll16(wprojT + (size_t)n * 256 + kt * 128 + (swl ^ ((n & 7) << 3)),
              Bs + c * 512);
      }
      __syncthreads();
      #pragma unroll
      for (int ks = 0; ks < 4; ks++) {
        const int kc = ks * 32 + kq * 8;
        const int ar = wm + lm;
        bf16x8 a = *(const bf16x8*)(&As[ar * 128 + (kc ^ ((ar & 7) << 3))]);
        #pragma unroll
        for (int tj = 0; tj < 4; tj++) {
          const int n = wn + tj * 16 + lm;
          bf16x8 b = *(const bf16x8*)(&Bs[n * 128 + (kc ^ ((n & 7) << 3))]);
          acc_p[tj] = __builtin_amdgcn_mfma_f32_16x16x32_bf16(a, b, acc_p[tj], 0, 0, 0);
        }
      }
      __syncthreads();
    }
    #pragma unroll
    for (int tj = 0; tj < 4; tj++) {
      const int n = wn + tj * 16 + lm;
      #pragma unroll
      for (int r = 0; r < 4; r++) {
        const int m = wm + kq * 4 + r;
        float v = acc_p[tj][r] + b_proj[n] + xres[(size_t)n * 8192 + bm + m];
        X1[m * 256 + n] = f2b(v);
      }
    }
    __syncthreads();
  }

  // ------------- fc1 (gelu) + fc2 partial, two 256-col halves --------------
  #pragma unroll
  for (int hf = 0; hf < 2; hf++) {
    f32x4 acc_h[4] = {};
    #pragma unroll
    for (int kt = 0; kt < 2; kt++) {
      #pragma unroll
      for (int s = 0; s < 8; s++) {
        const int c = w * 8 + s;
        const int n = c * 4 + rl;
        gll16(wfc1T + (size_t)(hf * 256 + n) * 256 + kt * 128 + (swl ^ ((n & 7) << 3)),
              Bs + c * 512);
      }
      __syncthreads();
      #pragma unroll
      for (int ks = 0; ks < 4; ks++) {
        const int kc = ks * 32 + kq * 8;
        const int ar = wm + lm;
        bf16x8 a = *(const bf16x8*)(&X1[ar * 256 + kt * 128 + kc]);
        #pragma unroll
        for (int tj = 0; tj < 4; tj++) {
          const int n = wn + tj * 16 + lm;
          bf16x8 b = *(const bf16x8*)(&Bs[n * 128 + (kc ^ ((n & 7) << 3))]);
          acc_h[tj] = __builtin_amdgcn_mfma_f32_16x16x32_bf16(a, b, acc_h[tj], 0, 0, 0);
        }
      }
      __syncthreads();
    }
    #pragma unroll
    for (int tj = 0; tj < 4; tj++) {
      const int n = wn + tj * 16 + lm;
      #pragma unroll
      for (int r = 0; r < 4; r++) {
        const int m = wm + kq * 4 + r;
        float v = acc_h[tj][r] + b_fc1[hf * 256 + n];
        v = 0.5f * v * (1.0f + erff(v * 0.70710678118f));
        Hs[m * 256 + n] = f2b(v);
      }
    }
    __syncthreads();

    #pragma unroll
    for (int kt = 0; kt < 2; kt++) {
      #pragma unroll
      for (int s = 0; s < 8; s++) {
        const int c = w * 8 + s;
        const int n = c * 4 + rl;
        gll16(wfc2T + (size_t)n * 512 + hf * 256 + kt * 128 + (swl ^ ((n & 7) << 3)),
              Bs + c * 512);
      }
      __syncthreads();
      #pragma unroll
      for (int ks = 0; ks < 4; ks++) {
        const int kc = ks * 32 + kq * 8;
        const int ar = wm + lm;
        bf16x8 a = *(const bf16x8*)(&Hs[ar * 256 + kt * 128 + kc]);
        #pragma unroll
        for (int tj = 0; tj < 4; tj++) {
          const int n = wn + tj * 16 + lm;
          bf16x8 b = *(const bf16x8*)(&Bs[n * 128 + (kc ^ ((n & 7) << 3))]);
          acc_o[tj] = __builtin_amdgcn_mfma_f32_16x16x32_bf16(a, b, acc_o[tj], 0, 0, 0);
        }
      }
      __syncthreads();
    }
  }

  // ---------------- fc2 epilogue: + b_fc2 + x1 residual, f32 chw -----------
  #pragma unroll
  for (int tj = 0; tj < 4; tj++) {
    const int n  = wn + tj * 16 + lm;
    const int m0 = wm + kq * 4;
    float4 v;
    float* vp = &v.x;
    #pragma unroll
    for (int r = 0; r < 4; r++)
      vp[r] = acc_o[tj][r] + b_fc2[n] + b2f(X1[(m0 + r) * 256 + n]);
    *(float4*)(out + (size_t)n * 8192 + bm + m0) = v;
  }
}

// ---------------------------------------------------------------------------
extern "C" void kernel_launch(void* const* d_in, const int* in_sizes, int n_in,
                              void* d_out, int out_size, void* d_ws, size_t ws_size,
                              hipStream_t stream)
{
  const float* x      = (const float*)d_in[0];
  const float* w_qkv  = (const float*)d_in[1];
  const float* b_qkv  = (const float*)d_in[2];
  const float* rpb    = (const float*)d_in[3];
  const float* w_proj = (const float*)d_in[4];
  const float* b_proj = (const float*)d_in[5];
  const float* w_fc1  = (const float*)d_in[6];
  const float* b_fc1  = (const float*)d_in[7];
  const float* w_fc2  = (const float*)d_in[8];
  const float* b_fc2  = (const float*)d_in[9];
  float* out = (float*)d_out;

  const int M = 8192;
  char* ws = (char*)d_ws;
  ushort* att    = (ushort*)(ws);               //  4,194,304 B (was xb slot)
  ushort* qkv    = (ushort*)(ws + 4194304);     // 12,582,912 B
  ushort* wqkvT  = (ushort*)(ws + 20971520);    //    393,216 B
  ushort* wprojT = (ushort*)(ws + 21364736);    //    131,072 B
  ushort* wfc1T  = (ushort*)(ws + 21495808);    //    262,144 B
  ushort* wfc2T  = (ushort*)(ws + 21757952);    //    262,144 B
  ushort* vT     = (ushort*)(ws + 22020096);    //  4,194,304 B + 64K pad

  dim3 blk(256);

  prep_kernel<<<dim3(512), blk, 0, stream>>>(
      w_qkv, w_proj, w_fc1, w_fc2, wqkvT, wprojT, wfc1T, wfc2T);

  // qkv = x^T @ wqkvT^T + b_qkv (A-transpose fused) -> q,k rows + vT
  gemm_qkv<<<dim3(768 / 128, M / 128), blk, 0, stream>>>(
      x, wqkvT, b_qkv, qkv, vT);

  natt_mfma<<<dim3(512, 2), blk, 0, stream>>>(qkv, vT, rpb, att);

  // out = fc2(gelu(fc1(proj(att)+x))) + x1, all in one kernel (v1)
  mlp_fused<<<dim3(256), dim3(512), 0, stream>>>(
      att, wprojT, wfc1T, wfc2T, b_proj, b_fc1, b_fc2, x, out);
}